// Round 4
// baseline (1267.879 us; speedup 1.0000x reference)
//
#include <hip/hip_runtime.h>

// ---------------------------------------------------------------------------
// BidirectionalMLP equilibrium relaxation on MI355X.
// s1,s2: [256,4096], s3: [256,10].  25 steps of:
//   s1' = clip(0.5*s1 + CC + 0.25*(r2@bw1))          CC = 0.25*(rx@fw0), const
//   s2' = clip(0.5*s2 + 0.25*(r1@fw1) + 0.25*(r3@bw2))
//   s3' = clip((0.5-beta)*s3 + 0.5*(r2@fw2) + beta*y)
// bf16 MFMA 16x16x32, fp32 accum. Weights transposed once to [N][K] bf16.
// Round 7: resubmit of round 6 (container infra flake, no kernel verdict).
// LDS-bandwidth geometry fix. Round-5 counters (41.3us, MfmaUtil 15%,
// 775cy/K-step vs ~565cy of LDS traffic) showed the 64x64/2x2 tile reads
// 8 B of LDS per output element. Now 64x128 tiles, 2x2 waves of 32x64
// (6 B/elem, -26% LDS traffic), grid 256 = 1 block/CU, ring-4 LDS (104 KB),
// prefetch depth 3, counted gates vmcnt(12)/(6)/(0) (stages are 6 loads per
// thread: 2 A + 4 B). Counted gates carry the overlap intra-block (m201
// precedent: 1 block/CU + counted vmcnt = 62% MfmaUtil). Numerics identical
// to round 5 (same MFMA shapes, same K order, same f32 s3-dot epilogue).
// ---------------------------------------------------------------------------

typedef __attribute__((ext_vector_type(4))) float f32x4;
typedef __attribute__((ext_vector_type(8))) short short8;

__device__ __forceinline__ unsigned short f2b(float f) {
    union { float f; unsigned int u; } v;
    v.f = f;
    unsigned int r = v.u + 0x7fffu + ((v.u >> 16) & 1u);
    return (unsigned short)(r >> 16);
}

__device__ __forceinline__ float clamp01(float v) {
    return fminf(fmaxf(v, 0.0f), 1.0f);
}

__device__ __forceinline__ void async16(const unsigned short* g, unsigned short* l) {
    __builtin_amdgcn_global_load_lds(
        (__attribute__((address_space(1))) void*)g,
        (__attribute__((address_space(3))) void*)l,
        16, 0, 0);
}

// LDS tiles: rows of 8 chunks (16B each); chunk position within a row is
// XOR-swizzled by (row&7) applied to the GLOBAL source k-chunk so the LDS
// destination stays linear (global_load_lds requirement) while ds_read_b128
// fragment reads spread banks.
__device__ __forceinline__ short8 frag_ld(const unsigned short* lds, int row, int ksel) {
    int chunk = (row << 3) + (ksel ^ (row & 7));
    return *reinterpret_cast<const short8*>(lds + (chunk << 3));
}

#define MFMA_BF16 __builtin_amdgcn_mfma_f32_16x16x32_bf16

// Core: C[64x128] tile of A[256,K] @ B^T[N,K] at (M0,N0). 256 threads, 4 waves
// in 2x2 layout (each wave 32x64: 2 M-frags x 4 N-frags). BK=64, 4-slot ring,
// prefetch depth 3. Steady-state K-step:
//   vmcnt(12)   -- own 6 loads of tile ks complete (2 newer stages in flight)
//   s_barrier   -- all waves' tile-ks loads complete -> slot valid
//   ds_read frags of slot ks&3 (2 A + 8 B reads over 2 ki)
//   stage tile ks+3 into slot (ks+3)&3 = (ks-1)&3 (read one barrier ago;
//     every wave's reads of that slot were consumed by its MFMAs before it
//     crossed the iteration-top barrier, so writes can't land on live reads)
//   MFMA x16 (+4 for s3 head)
// vmcnt NEVER drains to 0 in the main loop; tail peeled with vmcnt(6)/(0).
// s3blk: block-uniform flag; waves 0,1 additionally stage FW2T[16x64] per
// slot (their gates over-wait by <=2 loads: harmless, 4 blocks only).
__device__ __forceinline__ void gemm_core(
    const unsigned short* __restrict__ Ag,
    const unsigned short* __restrict__ Bg,
    int K, int M0, int N0,
    unsigned short (*ldsA)[64 * 64], unsigned short (*ldsB)[128 * 64],
    unsigned short (*ldsS)[16 * 64],
    f32x4* acc,
    const unsigned short* __restrict__ FW2T, f32x4* acc2,
    bool s3blk, bool doS3,
    int tid)
{
    const int lane = tid & 63;
    const int wave = tid >> 6;
    const int wm = (wave >> 1) << 5;   // 0 / 32
    const int wn = (wave & 1) << 6;    // 0 / 64
    const int fr = lane & 15;
    const int fq = lane >> 4;
    const int nks = K >> 6;

    auto STAGE = [&](int ks) {
        const int slot = ks & 3;
        const int k0 = ks << 6;
        unsigned short* lA = ldsA[slot];
        unsigned short* lB = ldsB[slot];
#pragma unroll
        for (int r = 0; r < 2; ++r) {  // A: 64 rows x 8 chunks = 512
            int ca = (r << 8) + tid;
            int row = ca >> 3, kcs = ca & 7;
            int kc = kcs ^ (row & 7);
            async16(Ag + (size_t)(M0 + row) * K + k0 + (kc << 3), lA + (ca << 3));
        }
#pragma unroll
        for (int r = 0; r < 4; ++r) {  // B: 128 rows x 8 chunks = 1024
            int cb = (r << 8) + tid;
            int row = cb >> 3, kcs = cb & 7;
            int kc = kcs ^ (row & 7);
            async16(Bg + (size_t)(N0 + row) * K + k0 + (kc << 3), lB + (cb << 3));
        }
        if (s3blk && tid < 128) {      // FW2T: 16 rows x 8 chunks = 128
            int row = tid >> 3, kcs = tid & 7;
            int kc = kcs ^ (row & 7);
            async16(FW2T + (size_t)row * 4096 + k0 + (kc << 3),
                    ldsS[slot] + (tid << 3));
        }
    };

    auto BODY = [&](int ks, bool doStage) {
        const int slot = ks & 3;
        const unsigned short* lA = ldsA[slot];
        const unsigned short* lB = ldsB[slot];
        short8 A0[2], A1[2], Bf[2][4], BS[2];
#pragma unroll
        for (int ki = 0; ki < 2; ++ki) {
            const int ksel = (ki << 2) + fq;
            A0[ki] = frag_ld(lA, wm + fr, ksel);
            A1[ki] = frag_ld(lA, wm + 16 + fr, ksel);
#pragma unroll
            for (int nf = 0; nf < 4; ++nf)
                Bf[ki][nf] = frag_ld(lB, wn + (nf << 4) + fr, ksel);
            if (doS3) BS[ki] = frag_ld(ldsS[slot], fr, ksel);
        }
        if (doStage) STAGE(ks + 3);
#pragma unroll
        for (int ki = 0; ki < 2; ++ki) {
#pragma unroll
            for (int nf = 0; nf < 4; ++nf) {
                acc[nf]     = MFMA_BF16(A0[ki], Bf[ki][nf], acc[nf], 0, 0, 0);
                acc[4 + nf] = MFMA_BF16(A1[ki], Bf[ki][nf], acc[4 + nf], 0, 0, 0);
            }
            if (doS3) {
                acc2[0] = MFMA_BF16(A0[ki], BS[ki], acc2[0], 0, 0, 0);
                acc2[1] = MFMA_BF16(A1[ki], BS[ki], acc2[1], 0, 0, 0);
            }
        }
    };

    STAGE(0); STAGE(1); STAGE(2);      // 3 tiles in flight

    int ks = 0;
    for (; ks < nks - 2; ++ks) {
        asm volatile("s_waitcnt vmcnt(12)" ::: "memory");
        __builtin_amdgcn_s_barrier();
        asm volatile("" ::: "memory");
        BODY(ks, ks + 3 < nks);
    }
    asm volatile("s_waitcnt vmcnt(6)" ::: "memory");
    __builtin_amdgcn_s_barrier();
    asm volatile("" ::: "memory");
    BODY(nks - 2, false);
    asm volatile("s_waitcnt vmcnt(0)" ::: "memory");
    __builtin_amdgcn_s_barrier();
    asm volatile("" ::: "memory");
    BODY(nks - 1, false);
}

// One relaxation step. Grid = 256 blocks: [0,128) GEMM1 (-> s1, s3),
// [128,256) GEMM2 (-> s2). 64x128 tiles over [256, 4096]. nt is the fast
// block index so panel-mates (b, b+32, ...) land on the same XCD (32%8==0).
__global__ __launch_bounds__(256) void step_kernel(
    const unsigned short* __restrict__ R2old,
    const unsigned short* __restrict__ R1old,
    const float* __restrict__ S1old, const float* __restrict__ S2old,
    const float* __restrict__ S3old,
    float* __restrict__ S1new, float* __restrict__ S2new, float* __restrict__ S3new,
    unsigned short* __restrict__ R1new, unsigned short* __restrict__ R2new,
    const unsigned short* __restrict__ B1T, const unsigned short* __restrict__ B2T,
    const unsigned short* __restrict__ FW2T,
    const float* __restrict__ CC, const float* __restrict__ bw2,
    const float* __restrict__ y, float beta)
{
    __shared__ __align__(16) unsigned short ldsA[4][64 * 64];
    __shared__ __align__(16) unsigned short ldsB[4][128 * 64];
    __shared__ __align__(16) unsigned short ldsS[4][16 * 64];
    const int tid = threadIdx.x;
    const int b = blockIdx.x;
    const bool g1 = (b < 128);
    int mt, nt;
    const unsigned short *A, *B;
    if (g1) { mt = b >> 5; nt = b & 31; A = R2old; B = B1T; }
    else    { int bb = b - 128; mt = bb >> 5; nt = bb & 31; A = R1old; B = B2T; }
    const int M0 = mt << 6, N0 = nt << 7;

    const int lane = tid & 63;
    const int wave = tid >> 6;
    const int wm = (wave >> 1) << 5;   // 0 / 32
    const int wn = (wave & 1) << 6;    // 0 / 64
    const int fr = lane & 15;
    const int fq = lane >> 4;
    const bool s3blk = g1 && (nt == 0);          // block-uniform
    const bool doS3 = s3blk && (wn == 0);        // wave-uniform (waves 0,2)

    f32x4 acc[8], acc2[2];
    f32x4 zero = {0.f, 0.f, 0.f, 0.f};
#pragma unroll
    for (int i = 0; i < 8; ++i) acc[i] = zero;
    acc2[0] = zero; acc2[1] = zero;

    gemm_core(A, B, 4096, M0, N0, ldsA, ldsB, ldsS, acc,
              FW2T, acc2, s3blk, doS3, tid);

    if (g1) {
#pragma unroll
        for (int m = 0; m < 2; ++m) {
#pragma unroll
            for (int nf = 0; nf < 4; ++nf) {
                int n = N0 + wn + (nf << 4) + fr;
                f32x4 av = acc[(m << 2) + nf];
#pragma unroll
                for (int rr = 0; rr < 4; ++rr) {
                    int mm = M0 + wm + (m << 4) + (fq << 2) + rr;
                    size_t o = (size_t)mm * 4096 + n;
                    float v = 0.5f * S1old[o] + CC[o] + 0.25f * av[rr];
                    v = clamp01(v);
                    S1new[o] = v;
                    R1new[o] = f2b(v);
                }
            }
        }
        if (doS3 && fr < 10) {
#pragma unroll
            for (int m = 0; m < 2; ++m) {
#pragma unroll
                for (int rr = 0; rr < 4; ++rr) {
                    int mm = M0 + wm + (m << 4) + (fq << 2) + rr;
                    float s3 = S3old[mm * 10 + fr];
                    float v = (0.5f - beta) * s3 + 0.5f * acc2[m][rr]
                              + beta * y[mm * 10 + fr];
                    v = clamp01(v);
                    S3new[mm * 10 + fr] = v;
                }
            }
        }
    } else {
#pragma unroll
        for (int m = 0; m < 2; ++m) {
#pragma unroll
            for (int nf = 0; nf < 4; ++nf) {
                int n = N0 + wn + (nf << 4) + fr;
                f32x4 av = acc[(m << 2) + nf];
#pragma unroll
                for (int rr = 0; rr < 4; ++rr) {
                    int mm = M0 + wm + (m << 4) + (fq << 2) + rr;
                    size_t o = (size_t)mm * 4096 + n;
                    float dot = 0.f;
#pragma unroll
                    for (int j = 0; j < 10; ++j)
                        dot += S3old[mm * 10 + j] * bw2[j * 4096 + n];
                    float v = 0.5f * S2old[o] + 0.25f * av[rr] + 0.25f * dot;
                    v = clamp01(v);
                    S2new[o] = v;
                    R2new[o] = f2b(v);
                }
            }
        }
    }
}

// CC = 0.25*(rx @ fw0). A = RX [256,1024] bf16, B = FW0T [4096,1024] bf16.
// 64x128 tiles -> 128 blocks.
__global__ __launch_bounds__(256) void c1_kernel(
    const unsigned short* __restrict__ RX,
    const unsigned short* __restrict__ FW0T,
    float* __restrict__ CC)
{
    __shared__ __align__(16) unsigned short ldsA[4][64 * 64];
    __shared__ __align__(16) unsigned short ldsB[4][128 * 64];
    __shared__ __align__(16) unsigned short ldsS[4][16 * 64];
    const int tid = threadIdx.x;
    const int b = blockIdx.x;
    const int mt = b >> 5, nt = b & 31;
    const int M0 = mt << 6, N0 = nt << 7;

    f32x4 acc[8], acc2[2];
    f32x4 zero = {0.f, 0.f, 0.f, 0.f};
#pragma unroll
    for (int i = 0; i < 8; ++i) acc[i] = zero;
    acc2[0] = zero; acc2[1] = zero;

    gemm_core(RX, FW0T, 1024, M0, N0, ldsA, ldsB, ldsS, acc,
              nullptr, acc2, false, false, tid);

    const int lane = tid & 63;
    const int wave = tid >> 6;
    const int wm = (wave >> 1) << 5;
    const int wn = (wave & 1) << 6;
    const int fr = lane & 15;
    const int fq = lane >> 4;
#pragma unroll
    for (int m = 0; m < 2; ++m) {
#pragma unroll
        for (int nf = 0; nf < 4; ++nf) {
            int n = N0 + wn + (nf << 4) + fr;
            f32x4 av = acc[(m << 2) + nf];
#pragma unroll
            for (int rr = 0; rr < 4; ++rr) {
                int mm = M0 + wm + (m << 4) + (fq << 2) + rr;
                CC[(size_t)mm * 4096 + n] = 0.25f * av[rr];
            }
        }
    }
}

// src [R][C] fp32 row-major -> dst [C][R] bf16 (dst row stride = R).
__global__ __launch_bounds__(256) void transpose_cvt(
    const float* __restrict__ src, unsigned short* __restrict__ dst,
    int R, int C)
{
    __shared__ float t[32][33];
    const int c0 = blockIdx.x << 5, r0 = blockIdx.y << 5;
    const int tx = threadIdx.x & 31, ty = threadIdx.x >> 5;   // ty: 0..7
#pragma unroll
    for (int i = 0; i < 32; i += 8)
        t[ty + i][tx] = src[(size_t)(r0 + ty + i) * C + (c0 + tx)];
    __syncthreads();
#pragma unroll
    for (int i = 0; i < 32; i += 8)
        dst[(size_t)(c0 + ty + i) * R + (r0 + tx)] = f2b(t[tx][ty + i]);
}

// FW2T fill, rx convert, zero-init of ping buffers.
__global__ __launch_bounds__(256) void misc_init(
    const float* __restrict__ x, const float* __restrict__ fw2,
    unsigned short* __restrict__ FW2T, unsigned short* __restrict__ RX,
    float* __restrict__ S1, float* __restrict__ S2, float* __restrict__ S3,
    unsigned short* __restrict__ R1, unsigned short* __restrict__ R2)
{
    const int stride = gridDim.x * blockDim.x;
    const int t0 = blockIdx.x * blockDim.x + threadIdx.x;
    for (int i = t0; i < 16 * 4096; i += stride) {      // FW2T[n][k] = fw2[k][n]
        int n = i >> 12, k = i & 4095;
        FW2T[i] = (n < 10) ? f2b(fw2[k * 10 + n]) : (unsigned short)0;
    }
    for (int i = t0; i < 256 * 1024; i += stride)
        RX[i] = f2b(clamp01(x[i]));
    for (int i = t0; i < 256 * 4096; i += stride) {
        S1[i] = 0.f; S2[i] = 0.f; R1[i] = 0; R2[i] = 0;
    }
    for (int i = t0; i < 2560; i += stride) S3[i] = 0.f;
}

__global__ __launch_bounds__(256) void pack_kernel(
    const float* __restrict__ S1, const float* __restrict__ S2,
    const float* __restrict__ S3, float* __restrict__ out)
{
    const int stride = gridDim.x * blockDim.x;
    for (int i = blockIdx.x * blockDim.x + threadIdx.x; i < 256 * 8202; i += stride) {
        int m = i / 8202, c = i - m * 8202;
        float v;
        if (c < 4096)       v = S1[(size_t)m * 4096 + c];
        else if (c < 8192)  v = S2[(size_t)m * 4096 + (c - 4096)];
        else                v = S3[m * 10 + (c - 8192)];
        out[i] = v;
    }
}

extern "C" void kernel_launch(void* const* d_in, const int* in_sizes, int n_in,
                              void* d_out, int out_size, void* d_ws, size_t ws_size,
                              hipStream_t stream) {
    const float* x   = (const float*)d_in[0];
    const float* fw0 = (const float*)d_in[1];
    const float* fw1 = (const float*)d_in[2];
    const float* fw2 = (const float*)d_in[3];
    // d_in[4] = bw0 : unused by the reference
    const float* bw1 = (const float*)d_in[5];
    const float* bw2 = (const float*)d_in[6];
    const float* y   = (const float*)d_in[7];

    char* ws = (char*)d_ws;
    // workspace layout (bytes)
    unsigned short* B1T  = (unsigned short*)(ws + 0);          // 4096x4096 bf16
    unsigned short* B2T  = (unsigned short*)(ws + 33554432);   // 4096x4096 bf16
    unsigned short* FW0T = (unsigned short*)(ws + 67108864);   // 4096x1024 bf16
    unsigned short* FW2T = (unsigned short*)(ws + 75497472);   // 16x4096 bf16
    unsigned short* RX   = (unsigned short*)(ws + 75628544);   // 256x1024 bf16
    float*          CC   = (float*)(ws + 76152832);            // 256x4096 f32
    float*          S1f  = (float*)(ws + 80347136);            // 2 x 256x4096 f32
    float*          S2f  = (float*)(ws + 88735744);            // 2 x 256x4096 f32
    float*          S3f  = (float*)(ws + 97124352);            // 2 x 256x10 f32
    unsigned short* R1   = (unsigned short*)(ws + 97144832);   // 2 x 256x4096 bf16
    unsigned short* R2   = (unsigned short*)(ws + 101339136);  // 2 x 256x4096 bf16
    // total ~105.6 MB

    const size_t SB = 256 * 4096;  // state buffer elems
    dim3 blk(256);

    transpose_cvt<<<dim3(128, 128), blk, 0, stream>>>(bw1, B1T, 4096, 4096);
    transpose_cvt<<<dim3(128, 128), blk, 0, stream>>>(fw1, B2T, 4096, 4096);
    transpose_cvt<<<dim3(128, 32),  blk, 0, stream>>>(fw0, FW0T, 1024, 4096);
    misc_init<<<512, blk, 0, stream>>>(x, fw2, FW2T, RX,
                                       S1f, S2f, S3f, R1, R2);
    c1_kernel<<<128, blk, 0, stream>>>(RX, FW0T, CC);

    for (int t = 0; t < 25; ++t) {
        const int o = t & 1, nw = o ^ 1;
        const float beta = (t < 20) ? 0.0f : 0.5f;
        step_kernel<<<256, blk, 0, stream>>>(
            R2 + o * SB, R1 + o * SB,
            S1f + o * SB, S2f + o * SB, S3f + o * 2560,
            S1f + nw * SB, S2f + nw * SB, S3f + nw * 2560,
            R1 + nw * SB, R2 + nw * SB,
            B1T, B2T, FW2T, CC, bw2, y, beta);
    }

    pack_kernel<<<2048, blk, 0, stream>>>(S1f + SB, S2f + SB, S3f + 2560,
                                          (float*)d_out);
}

// Round 5
// 1215.368 us; speedup vs baseline: 1.0432x; 1.0432x over previous
//
#include <hip/hip_runtime.h>

// ---------------------------------------------------------------------------
// BidirectionalMLP equilibrium relaxation on MI355X.
// s1,s2: [256,4096], s3: [256,10].  25 steps of:
//   s1' = clip(0.5*s1 + CC + 0.25*(r2@bw1))          CC = 0.25*(rx@fw0), const
//   s2' = clip(0.5*s2 + 0.25*(r1@fw1) + 0.25*(r3@bw2))
//   s3' = clip((0.5-beta)*s3 + 0.5*(r2@fw2) + beta*y)
// bf16 MFMA 16x16x32, fp32 accum.
// Round 8: dual-port operand split. Round-2 re-analysis: 1549 cy/pair vs
// LDS 758 + MFMA 310 -> ports serialized by the per-iter convoy, LDS only
// 49% busy. Now: A stays on the LDS ring (global_load_lds + ds_read,
// counted vmcnt(8) gates, depth-3); B moves to direct global->register
// loads from a FRAG-MAJOR layout (one lane-linear 1KB dwordx4 per frag,
// depth-2 register prefetch, pipelined by the compiler's exact per-register
// vmcnt tracking). LDS and TCP/L1 ports now run concurrently. Grid 512 =
// 2 blocks/CU. Epilogues/state layouts/rounding identical to round 2;
// weights pre-swizzled once by fragize_T (replaces transpose_cvt).
// Frag-major layout: F[rb][ks][ki][fq][fr][j] = M[rb*16+fr][ks*64+ki*32+fq*8+j]
// so a wave's frag load for (rb,ks,ki) is base + lane*16 bytes, contiguous.
// ---------------------------------------------------------------------------

typedef __attribute__((ext_vector_type(4))) float f32x4;
typedef __attribute__((ext_vector_type(8))) short short8;

__device__ __forceinline__ unsigned short f2b(float f) {
    union { float f; unsigned int u; } v;
    v.f = f;
    unsigned int r = v.u + 0x7fffu + ((v.u >> 16) & 1u);
    return (unsigned short)(r >> 16);
}

__device__ __forceinline__ float clamp01(float v) {
    return fminf(fmaxf(v, 0.0f), 1.0f);
}

__device__ __forceinline__ void async16(const unsigned short* g, unsigned short* l) {
    __builtin_amdgcn_global_load_lds(
        (__attribute__((address_space(1))) void*)g,
        (__attribute__((address_space(3))) void*)l,
        16, 0, 0);
}

// A-tile LDS: rows of 8 chunks (16B each); chunk position within a row is
// XOR-swizzled by (row&7) applied to the GLOBAL source k-chunk so the LDS
// destination stays linear (global_load_lds requirement) while ds_read_b128
// fragment reads spread banks.
__device__ __forceinline__ short8 frag_ld(const unsigned short* lds, int row, int ksel) {
    int chunk = (row << 3) + (ksel ^ (row & 7));
    return *reinterpret_cast<const short8*>(lds + (chunk << 3));
}

#define MFMA_BF16 __builtin_amdgcn_mfma_f32_16x16x32_bf16

// Core: C[64x64] tile of A[256,K] @ B^T[N,K] at (M0,N0). 256 threads, 4 waves
// 2x2 (each wave 32x32). BK=64. A: 4-slot LDS ring, staged depth-3, gate
// vmcnt(8) (reorder-robust: >=10 VMEM ops separate a stage from its gate,
// so the gate always retires it; B-register deps are tracked exactly by the
// compiler's own s_waitcnt insertion). B: frag-major direct loads, 2 register
// sets alternating per K-step, reloaded depth-2 right after consumption.
// Per iter: gate -> barrier -> ds_read A -> MFMA(Bcur) -> reload Bcur(ks+2)
// -> stage A(ks+3). vmcnt never drains to 0 in the main loop.
__device__ __forceinline__ void gemm_core(
    const unsigned short* __restrict__ Ag,
    const unsigned short* __restrict__ BF,
    int K, int M0, int N0,
    unsigned short (*ldsA)[64 * 64],
    f32x4* acc,
    const unsigned short* __restrict__ FW2F, f32x4* acc2, bool doS3,
    int tid)
{
    const int lane = tid & 63;
    const int wave = tid >> 6;
    const int wm = (wave >> 1) << 5;   // 0 / 32
    const int wn = (wave & 1) << 5;    // 0 / 32
    const int fr = lane & 15;
    const int fq = lane >> 4;
    const int nks = K >> 6;

    // B frag stream bases (include lane offset). rb0 = first 16-col block.
    const int rb0 = (N0 + wn) >> 4;
    const unsigned short* bp0 = BF + ((size_t)rb0 * nks * 2) * 512 + lane * 8;
    const unsigned short* bp1 = bp0 + (size_t)nks * 1024;   // rb0+1
    const unsigned short* sp  = FW2F + lane * 8;            // rb=0, nks=64

    auto STAGE = [&](int ks) {
        const int slot = ks & 3;
        const int k0 = ks << 6;
        unsigned short* lA = ldsA[slot];
#pragma unroll
        for (int r = 0; r < 2; ++r) {  // A: 64 rows x 8 chunks = 512
            int ca = (r << 8) + tid;
            int row = ca >> 3, kcs = ca & 7;
            int kc = kcs ^ (row & 7);
            async16(Ag + (size_t)(M0 + row) * K + k0 + (kc << 3), lA + (ca << 3));
        }
    };

    auto LOADB = [&](short8 (&b0)[2], short8 (&b1)[2], short8 (&bs)[2], int ks) {
        const unsigned short* p0 = bp0 + (size_t)ks * 1024;
        b0[0] = *reinterpret_cast<const short8*>(p0);
        b0[1] = *reinterpret_cast<const short8*>(p0 + 512);
        const unsigned short* p1 = bp1 + (size_t)ks * 1024;
        b1[0] = *reinterpret_cast<const short8*>(p1);
        b1[1] = *reinterpret_cast<const short8*>(p1 + 512);
        if (doS3) {
            const unsigned short* ps = sp + (size_t)ks * 1024;
            bs[0] = *reinterpret_cast<const short8*>(ps);
            bs[1] = *reinterpret_cast<const short8*>(ps + 512);
        }
    };

    auto ITER = [&](int ks, short8 (&b0)[2], short8 (&b1)[2], short8 (&bs)[2],
                    bool reloadB, bool lastGate) {
        if (lastGate) asm volatile("s_waitcnt vmcnt(4)" ::: "memory");
        else          asm volatile("s_waitcnt vmcnt(8)" ::: "memory");
        __builtin_amdgcn_s_barrier();
        asm volatile("" ::: "memory");
        const unsigned short* lA = ldsA[ks & 3];
        short8 a0[2], a1[2];
#pragma unroll
        for (int ki = 0; ki < 2; ++ki) {
            const int ksel = (ki << 2) + fq;
            a0[ki] = frag_ld(lA, wm + fr, ksel);
            a1[ki] = frag_ld(lA, wm + 16 + fr, ksel);
        }
#pragma unroll
        for (int ki = 0; ki < 2; ++ki) {
            acc[0] = MFMA_BF16(a0[ki], b0[ki], acc[0], 0, 0, 0);
            acc[1] = MFMA_BF16(a0[ki], b1[ki], acc[1], 0, 0, 0);
            acc[2] = MFMA_BF16(a1[ki], b0[ki], acc[2], 0, 0, 0);
            acc[3] = MFMA_BF16(a1[ki], b1[ki], acc[3], 0, 0, 0);
            if (doS3) {
                acc2[0] = MFMA_BF16(a0[ki], bs[ki], acc2[0], 0, 0, 0);
                acc2[1] = MFMA_BF16(a1[ki], bs[ki], acc2[1], 0, 0, 0);
            }
        }
        if (reloadB) LOADB(b0, b1, bs, ks + 2);
        if (ks + 3 < nks) STAGE(ks + 3);
    };

    short8 s0b0[2], s0b1[2], s0bs[2];
    short8 s1b0[2], s1b1[2], s1bs[2];

    // Prologue: IA(0) IB(0) IA(1) IB(1) IA(2) -- steady invariant from ks=0.
    STAGE(0); LOADB(s0b0, s0b1, s0bs, 0);
    STAGE(1); LOADB(s1b0, s1b1, s1bs, 1);
    STAGE(2);

    int ks = 0;
    for (; ks < nks - 2; ks += 2) {
        ITER(ks,     s0b0, s0b1, s0bs, true, false);
        ITER(ks + 1, s1b0, s1b1, s1bs, true, false);
    }
    ITER(nks - 2, s0b0, s0b1, s0bs, false, false);
    ITER(nks - 1, s1b0, s1b1, s1bs, false, true);
}

// One relaxation step. Grid = 512 blocks: [0,256) GEMM1 (-> s1, s3),
// [256,512) GEMM2 (-> s2). 64x64 tiles over [256, 4096]. nt is the fast
// block index so panel-mates (b, b+64, ...) land on the same XCD (64%8==0).
__global__ __launch_bounds__(256) void step_kernel(
    const unsigned short* __restrict__ R2old,
    const unsigned short* __restrict__ R1old,
    const float* __restrict__ S1old, const float* __restrict__ S2old,
    const float* __restrict__ S3old,
    float* __restrict__ S1new, float* __restrict__ S2new, float* __restrict__ S3new,
    unsigned short* __restrict__ R1new, unsigned short* __restrict__ R2new,
    const unsigned short* __restrict__ B1F, const unsigned short* __restrict__ B2F,
    const unsigned short* __restrict__ FW2F,
    const float* __restrict__ CC, const float* __restrict__ bw2,
    const float* __restrict__ y, float beta)
{
    __shared__ __align__(16) unsigned short ldsA[4][64 * 64];
    const int tid = threadIdx.x;
    const int b = blockIdx.x;
    const bool g1 = (b < 256);
    int mt, nt;
    const unsigned short *A, *B;
    if (g1) { mt = b >> 6; nt = b & 63; A = R2old; B = B1F; }
    else    { int bb = b - 256; mt = bb >> 6; nt = bb & 63; A = R1old; B = B2F; }
    const int M0 = mt << 6, N0 = nt << 6;

    const int lane = tid & 63;
    const int wave = tid >> 6;
    const int wm = (wave >> 1) << 5;
    const int wn = (wave & 1) << 5;
    const int fr = lane & 15;
    const int fq = lane >> 4;
    const bool doS3 = g1 && (nt == 0) && (wn == 0);   // wave-uniform

    f32x4 acc[4], acc2[2];
    f32x4 zero = {0.f, 0.f, 0.f, 0.f};
#pragma unroll
    for (int i = 0; i < 4; ++i) acc[i] = zero;
    acc2[0] = zero; acc2[1] = zero;

    gemm_core(A, B, 4096, M0, N0, ldsA, acc, FW2F, acc2, doS3, tid);

    if (g1) {
#pragma unroll
        for (int i = 0; i < 4; ++i) {
            int im = i >> 1, in_ = i & 1;
            int n = N0 + wn + (in_ << 4) + fr;
#pragma unroll
            for (int rr = 0; rr < 4; ++rr) {
                int m = M0 + wm + (im << 4) + (fq << 2) + rr;
                size_t o = (size_t)m * 4096 + n;
                float v = 0.5f * S1old[o] + CC[o] + 0.25f * acc[i][rr];
                v = clamp01(v);
                S1new[o] = v;
                R1new[o] = f2b(v);
            }
        }
        if (doS3 && fr < 10) {
#pragma unroll
            for (int im = 0; im < 2; ++im) {
#pragma unroll
                for (int rr = 0; rr < 4; ++rr) {
                    int m = M0 + wm + (im << 4) + (fq << 2) + rr;
                    float s3 = S3old[m * 10 + fr];
                    float v = (0.5f - beta) * s3 + 0.5f * acc2[im][rr]
                              + beta * y[m * 10 + fr];
                    v = clamp01(v);
                    S3new[m * 10 + fr] = v;
                }
            }
        }
    } else {
#pragma unroll
        for (int i = 0; i < 4; ++i) {
            int im = i >> 1, in_ = i & 1;
            int n = N0 + wn + (in_ << 4) + fr;
#pragma unroll
            for (int rr = 0; rr < 4; ++rr) {
                int m = M0 + wm + (im << 4) + (fq << 2) + rr;
                size_t o = (size_t)m * 4096 + n;
                float dot = 0.f;
#pragma unroll
                for (int j = 0; j < 10; ++j)
                    dot += S3old[m * 10 + j] * bw2[j * 4096 + n];
                float v = 0.5f * S2old[o] + 0.25f * acc[i][rr] + 0.25f * dot;
                v = clamp01(v);
                S2new[o] = v;
                R2new[o] = f2b(v);
            }
        }
    }
}

// CC = 0.25*(rx @ fw0). A = RX [256,1024] bf16 row-major, B = FW0F frag-major.
// 64x64 tiles -> 256 blocks.
__global__ __launch_bounds__(256) void c1_kernel(
    const unsigned short* __restrict__ RX,
    const unsigned short* __restrict__ FW0F,
    float* __restrict__ CC)
{
    __shared__ __align__(16) unsigned short ldsA[4][64 * 64];
    const int tid = threadIdx.x;
    const int b = blockIdx.x;
    const int mt = b >> 6, nt = b & 63;
    const int M0 = mt << 6, N0 = nt << 6;

    f32x4 acc[4], acc2[2];
    f32x4 zero = {0.f, 0.f, 0.f, 0.f};
#pragma unroll
    for (int i = 0; i < 4; ++i) acc[i] = zero;
    acc2[0] = zero; acc2[1] = zero;

    gemm_core(RX, FW0F, 1024, M0, N0, ldsA, acc, FW0F, acc2, false, tid);

    const int lane = tid & 63;
    const int wave = tid >> 6;
    const int wm = (wave >> 1) << 5;
    const int wn = (wave & 1) << 5;
    const int fr = lane & 15;
    const int fq = lane >> 4;
#pragma unroll
    for (int i = 0; i < 4; ++i) {
        int im = i >> 1, in_ = i & 1;
        int n = N0 + wn + (in_ << 4) + fr;
#pragma unroll
        for (int rr = 0; rr < 4; ++rr) {
            int m = M0 + wm + (im << 4) + (fq << 2) + rr;
            CC[(size_t)m * 4096 + n] = 0.25f * acc[i][rr];
        }
    }
}

// src f32 [Kdim][R] row-major -> frag-major bf16 for matrix [R][Kdim]:
// dst[((rb*(K/64)+ks)*2+ki)*512 + fq*128 + fr*8 + j]
//   = f2b(src[(ks*64+ki*32+fq*8+j)*R + rb*16+fr]),  col < R else 0.
// grid: (R_pad/16, Kdim/64), 256 threads, LDS-bounced for coalesced reads.
__global__ __launch_bounds__(256) void fragize_T(
    const float* __restrict__ src, unsigned short* __restrict__ dst,
    int Kdim, int R)
{
    __shared__ float t[64][17];
    const int rb = blockIdx.x, ks = blockIdx.y;
    const int tid = threadIdx.x;
    const int NKS = Kdim >> 6;
    // read 64 k-rows x 16 cols, coalesced 64B per row-quad
    const int row = tid >> 2, seg = tid & 3;
    const int k = (ks << 6) + row;
#pragma unroll
    for (int i = 0; i < 4; ++i) {
        int c = (rb << 4) + (seg << 2) + i;
        t[row][(seg << 2) + i] = (c < R) ? src[(size_t)k * R + c] : 0.f;
    }
    __syncthreads();
    // write 2048B frag block: thread -> 4 bf16 (8B aligned)
    const int j0 = (tid & 1) << 2;
    const int fr = (tid >> 1) & 15;
    const int fq = (tid >> 5) & 3;
    const int ki = tid >> 7;
    unsigned int w0 = (unsigned int)f2b(t[(ki << 5) + (fq << 3) + j0 + 0][fr])
                    | ((unsigned int)f2b(t[(ki << 5) + (fq << 3) + j0 + 1][fr]) << 16);
    unsigned int w1 = (unsigned int)f2b(t[(ki << 5) + (fq << 3) + j0 + 2][fr])
                    | ((unsigned int)f2b(t[(ki << 5) + (fq << 3) + j0 + 3][fr]) << 16);
    size_t o = (((size_t)rb * NKS + ks) * 2 + ki) * 512 + (fq << 7) + (fr << 3) + j0;
    uint2 u; u.x = w0; u.y = w1;
    *reinterpret_cast<uint2*>(dst + o) = u;
}

// rx convert (row-major bf16, A-side of c1) + zero-init of ping buffers.
__global__ __launch_bounds__(256) void misc_init(
    const float* __restrict__ x, unsigned short* __restrict__ RX,
    float* __restrict__ S1, float* __restrict__ S2, float* __restrict__ S3,
    unsigned short* __restrict__ R1, unsigned short* __restrict__ R2)
{
    const int stride = gridDim.x * blockDim.x;
    const int t0 = blockIdx.x * blockDim.x + threadIdx.x;
    for (int i = t0; i < 256 * 1024; i += stride)
        RX[i] = f2b(clamp01(x[i]));
    for (int i = t0; i < 256 * 4096; i += stride) {
        S1[i] = 0.f; S2[i] = 0.f; R1[i] = 0; R2[i] = 0;
    }
    for (int i = t0; i < 2560; i += stride) S3[i] = 0.f;
}

__global__ __launch_bounds__(256) void pack_kernel(
    const float* __restrict__ S1, const float* __restrict__ S2,
    const float* __restrict__ S3, float* __restrict__ out)
{
    const int stride = gridDim.x * blockDim.x;
    for (int i = blockIdx.x * blockDim.x + threadIdx.x; i < 256 * 8202; i += stride) {
        int m = i / 8202, c = i - m * 8202;
        float v;
        if (c < 4096)       v = S1[(size_t)m * 4096 + c];
        else if (c < 8192)  v = S2[(size_t)m * 4096 + (c - 4096)];
        else                v = S3[m * 10 + (c - 8192)];
        out[i] = v;
    }
}

extern "C" void kernel_launch(void* const* d_in, const int* in_sizes, int n_in,
                              void* d_out, int out_size, void* d_ws, size_t ws_size,
                              hipStream_t stream) {
    const float* x   = (const float*)d_in[0];
    const float* fw0 = (const float*)d_in[1];
    const float* fw1 = (const float*)d_in[2];
    const float* fw2 = (const float*)d_in[3];
    // d_in[4] = bw0 : unused by the reference
    const float* bw1 = (const float*)d_in[5];
    const float* bw2 = (const float*)d_in[6];
    const float* y   = (const float*)d_in[7];

    char* ws = (char*)d_ws;
    // workspace layout (bytes) -- frag-major buffers, same sizes as before
    unsigned short* B1F  = (unsigned short*)(ws + 0);          // 4096x4096 bf16
    unsigned short* B2F  = (unsigned short*)(ws + 33554432);   // 4096x4096 bf16
    unsigned short* FW0F = (unsigned short*)(ws + 67108864);   // 4096x1024 bf16
    unsigned short* FW2F = (unsigned short*)(ws + 75497472);   // 16x4096 bf16
    unsigned short* RX   = (unsigned short*)(ws + 75628544);   // 256x1024 bf16
    float*          CC   = (float*)(ws + 76152832);            // 256x4096 f32
    float*          S1f  = (float*)(ws + 80347136);            // 2 x 256x4096 f32
    float*          S2f  = (float*)(ws + 88735744);            // 2 x 256x4096 f32
    float*          S3f  = (float*)(ws + 97124352);            // 2 x 256x10 f32
    unsigned short* R1   = (unsigned short*)(ws + 97144832);   // 2 x 256x4096 bf16
    unsigned short* R2   = (unsigned short*)(ws + 101339136);  // 2 x 256x4096 bf16
    // total ~105.6 MB

    const size_t SB = 256 * 4096;  // state buffer elems
    dim3 blk(256);

    fragize_T<<<dim3(256, 64), blk, 0, stream>>>(bw1, B1F, 4096, 4096);
    fragize_T<<<dim3(256, 64), blk, 0, stream>>>(fw1, B2F, 4096, 4096);
    fragize_T<<<dim3(256, 16), blk, 0, stream>>>(fw0, FW0F, 1024, 4096);
    fragize_T<<<dim3(1, 64),   blk, 0, stream>>>(fw2, FW2F, 4096, 10);
    misc_init<<<512, blk, 0, stream>>>(x, RX, S1f, S2f, S3f, R1, R2);
    c1_kernel<<<256, blk, 0, stream>>>(RX, FW0F, CC);

    for (int t = 0; t < 25; ++t) {
        const int o = t & 1, nw = o ^ 1;
        const float beta = (t < 20) ? 0.0f : 0.5f;
        step_kernel<<<512, blk, 0, stream>>>(
            R2 + o * SB, R1 + o * SB,
            S1f + o * SB, S2f + o * SB, S3f + o * 2560,
            S1f + nw * SB, S2f + nw * SB, S3f + nw * 2560,
            R1 + nw * SB, R2 + nw * SB,
            B1F, B2F, FW2F, CC, bw2, y, beta);
    }

    pack_kernel<<<2048, blk, 0, stream>>>(S1f + SB, S2f + SB, S3f + 2560,
                                          (float*)d_out);
}

// Round 6
// 1110.536 us; speedup vs baseline: 1.1417x; 1.0944x over previous
//
#include <hip/hip_runtime.h>

// ---------------------------------------------------------------------------
// BidirectionalMLP equilibrium relaxation on MI355X.
// s1,s2: [256,4096], s3: [256,10].  25 steps of:
//   s1' = clip(0.5*s1 + CC + 0.25*(r2@bw1))          CC = 0.25*(rx@fw0), const
//   s2' = clip(0.5*s2 + 0.25*(r1@fw1) + 0.25*(r3@bw2))
//   s3' = clip((0.5-beta)*s3 + 0.5*(r2@fw2) + beta*y)
// bf16 MFMA 16x16x32, fp32 accum. Weights transposed once to [N][K] bf16.
// Round 9: round-2 structure (proven 41.3us: 64x64 tiles, grid 512 = 2
// blocks/CU, 4-slot LDS ring, counted vmcnt gates, transpose_cvt setup)
// + ONE change: register fragment double-buffering. Iter ks prefetches the
// ks+1 fragments from the already-staged ring slot BEFORE running the ks
// MFMAs, so ds_read issue+latency hides under the MFMA phase; the compiler's
// own per-register lgkmcnt defers the wait to the next iteration's first
// MFMA (no inline lgkm -> no rule-18 hazard). Gate moves one tile deeper:
// vmcnt(4) retires stage ks+1 (stage ks+2 stays in flight); drains to 0 only
// in the last 2 iterations. Slot-write safety unchanged (writes to slot
// (ks-1)&3 separated from its last readers by two barriers). Ping-pong
// register sets are named (rule 20), loop unrolled x2 (nks even: 64, 16).
// Round-5 post-mortem: direct B-loads duplicated B across waves (L2 traffic
// 16->24 KB/block/K-step, ~+7us/step) -> neutral; LDS staging is
// traffic-optimal, only the serial chain needed breaking.
// ---------------------------------------------------------------------------

typedef __attribute__((ext_vector_type(4))) float f32x4;
typedef __attribute__((ext_vector_type(8))) short short8;

__device__ __forceinline__ unsigned short f2b(float f) {
    union { float f; unsigned int u; } v;
    v.f = f;
    unsigned int r = v.u + 0x7fffu + ((v.u >> 16) & 1u);
    return (unsigned short)(r >> 16);
}

__device__ __forceinline__ float clamp01(float v) {
    return fminf(fmaxf(v, 0.0f), 1.0f);
}

__device__ __forceinline__ void async16(const unsigned short* g, unsigned short* l) {
    __builtin_amdgcn_global_load_lds(
        (__attribute__((address_space(1))) void*)g,
        (__attribute__((address_space(3))) void*)l,
        16, 0, 0);
}

// LDS tiles: rows of 8 chunks (16B each); chunk position within a row is
// XOR-swizzled by (row&7) applied to the GLOBAL source k-chunk so the LDS
// destination stays linear (global_load_lds requirement) while ds_read_b128
// fragment reads spread banks.
__device__ __forceinline__ short8 frag_ld(const unsigned short* lds, int row, int ksel) {
    int chunk = (row << 3) + (ksel ^ (row & 7));
    return *reinterpret_cast<const short8*>(lds + (chunk << 3));
}

#define MFMA_BF16 __builtin_amdgcn_mfma_f32_16x16x32_bf16

// Core: C[64x64] tile of A[256,K] @ B^T[N,K] at (M0,N0). 256 threads, 4 waves
// 2x2 (each wave 32x32). BK=64, 4-slot ring, stage depth 3, register-set
// double buffer. Steady-state iteration ks:
//   vmcnt(4)    -- retire stage ks+1 (stage ks+2 stays in flight)
//   s_barrier   -- slot ks+1 valid for all waves
//   PREFETCH next reg set from slot (ks+1)&3   (ds_reads, no explicit wait)
//   STAGE(ks+3) into slot (ks-1)&3             (last read 2 barriers ago)
//   MFMA x16 on current reg set (+4 s3 head)   (ready since last iter)
// The compiler inserts the lgkmcnt for the prefetched set before its first
// use in the NEXT iteration -> ds_read latency hides under this iteration's
// MFMAs. vmcnt drains to 0 only at ks = nks-2. s3blk threads (tid<128)
// issue 5 loads/stage vs 4: gates over-wait by <=2 ops, safe.
__device__ __forceinline__ void gemm_core(
    const unsigned short* __restrict__ Ag,
    const unsigned short* __restrict__ Bg,
    int K, int M0, int N0,
    unsigned short (*ldsA)[64 * 64], unsigned short (*ldsB)[64 * 64],
    unsigned short (*ldsS)[16 * 64],
    f32x4* acc,
    const unsigned short* __restrict__ FW2T, f32x4* acc2,
    bool s3blk, bool doS3,
    int tid)
{
    const int lane = tid & 63;
    const int wave = tid >> 6;
    const int wm = (wave >> 1) << 5;   // 0 / 32
    const int wn = (wave & 1) << 5;    // 0 / 32
    const int fr = lane & 15;
    const int fq = lane >> 4;
    const int nks = K >> 6;

    auto STAGE = [&](int ks) {
        const int slot = ks & 3;
        const int k0 = ks << 6;
        unsigned short* lA = ldsA[slot];
        unsigned short* lB = ldsB[slot];
#pragma unroll
        for (int r = 0; r < 2; ++r) {  // A: 64 rows x 8 chunks = 512
            int ca = (r << 8) + tid;
            int row = ca >> 3, kcs = ca & 7;
            int kc = kcs ^ (row & 7);
            async16(Ag + (size_t)(M0 + row) * K + k0 + (kc << 3), lA + (ca << 3));
        }
#pragma unroll
        for (int r = 0; r < 2; ++r) {  // B: 64 rows x 8 chunks = 512
            int cb = (r << 8) + tid;
            int row = cb >> 3, kcs = cb & 7;
            int kc = kcs ^ (row & 7);
            async16(Bg + (size_t)(N0 + row) * K + k0 + (kc << 3), lB + (cb << 3));
        }
        if (s3blk && tid < 128) {      // FW2T: 16 rows x 8 chunks = 128
            int row = tid >> 3, kcs = tid & 7;
            int kc = kcs ^ (row & 7);
            async16(FW2T + (size_t)row * 4096 + k0 + (kc << 3),
                    ldsS[slot] + (tid << 3));
        }
    };

    auto PRE = [&](short8 (&A)[2][2], short8 (&B)[2][2], short8 (&S)[2], int ks) {
        const int slot = ks & 3;
        const unsigned short* lA = ldsA[slot];
        const unsigned short* lB = ldsB[slot];
#pragma unroll
        for (int ki = 0; ki < 2; ++ki) {
            const int ksel = (ki << 2) + fq;
            A[ki][0] = frag_ld(lA, wm + fr, ksel);
            A[ki][1] = frag_ld(lA, wm + 16 + fr, ksel);
            B[ki][0] = frag_ld(lB, wn + fr, ksel);
            B[ki][1] = frag_ld(lB, wn + 16 + fr, ksel);
            if (doS3) S[ki] = frag_ld(ldsS[slot], fr, ksel);
        }
    };

    auto MMA = [&](short8 (&A)[2][2], short8 (&B)[2][2], short8 (&S)[2]) {
#pragma unroll
        for (int ki = 0; ki < 2; ++ki) {
            acc[0] = MFMA_BF16(A[ki][0], B[ki][0], acc[0], 0, 0, 0);
            acc[1] = MFMA_BF16(A[ki][0], B[ki][1], acc[1], 0, 0, 0);
            acc[2] = MFMA_BF16(A[ki][1], B[ki][0], acc[2], 0, 0, 0);
            acc[3] = MFMA_BF16(A[ki][1], B[ki][1], acc[3], 0, 0, 0);
            if (doS3) {
                acc2[0] = MFMA_BF16(A[ki][0], S[ki], acc2[0], 0, 0, 0);
                acc2[1] = MFMA_BF16(A[ki][1], S[ki], acc2[1], 0, 0, 0);
            }
        }
    };

    short8 A0[2][2], B0[2][2], S0[2];
    short8 A1[2][2], B1[2][2], S1[2];

    STAGE(0); STAGE(1); STAGE(2);      // 3 tiles in flight

    asm volatile("s_waitcnt vmcnt(8)" ::: "memory");   // retire stage 0
    __builtin_amdgcn_s_barrier();
    asm volatile("" ::: "memory");
    PRE(A0, B0, S0, 0);

    for (int ks = 0; ks < nks; ks += 2) {
        // ---- even half: cur = set0, prefetch set1(ks+1) ----
        if (ks + 1 < nks) {
            if (ks + 2 < nks) asm volatile("s_waitcnt vmcnt(4)" ::: "memory");
            else              asm volatile("s_waitcnt vmcnt(0)" ::: "memory");
            __builtin_amdgcn_s_barrier();
            asm volatile("" ::: "memory");
            PRE(A1, B1, S1, ks + 1);
        }
        if (ks + 3 < nks) STAGE(ks + 3);
        MMA(A0, B0, S0);
        // ---- odd half: cur = set1, prefetch set0(ks+2) ----
        if (ks + 2 < nks) {
            if (ks + 3 < nks) asm volatile("s_waitcnt vmcnt(4)" ::: "memory");
            else              asm volatile("s_waitcnt vmcnt(0)" ::: "memory");
            __builtin_amdgcn_s_barrier();
            asm volatile("" ::: "memory");
            PRE(A0, B0, S0, ks + 2);
        }
        if (ks + 4 < nks) STAGE(ks + 4);
        MMA(A1, B1, S1);
    }
}

// One relaxation step. Grid = 512 blocks: [0,256) GEMM1 (-> s1, s3),
// [256,512) GEMM2 (-> s2). 64x64 tiles over [256, 4096]. nt is the fast
// block index so panel-mates (b, b+64, ...) land on the same XCD (64%8==0).
__global__ __launch_bounds__(256) void step_kernel(
    const unsigned short* __restrict__ R2old,
    const unsigned short* __restrict__ R1old,
    const float* __restrict__ S1old, const float* __restrict__ S2old,
    const float* __restrict__ S3old,
    float* __restrict__ S1new, float* __restrict__ S2new, float* __restrict__ S3new,
    unsigned short* __restrict__ R1new, unsigned short* __restrict__ R2new,
    const unsigned short* __restrict__ B1T, const unsigned short* __restrict__ B2T,
    const unsigned short* __restrict__ FW2T,
    const float* __restrict__ CC, const float* __restrict__ bw2,
    const float* __restrict__ y, float beta)
{
    __shared__ __align__(16) unsigned short ldsA[4][64 * 64];
    __shared__ __align__(16) unsigned short ldsB[4][64 * 64];
    __shared__ __align__(16) unsigned short ldsS[4][16 * 64];
    const int tid = threadIdx.x;
    const int b = blockIdx.x;
    const bool g1 = (b < 256);
    int mt, nt;
    const unsigned short *A, *B;
    if (g1) { mt = b >> 6; nt = b & 63; A = R2old; B = B1T; }
    else    { int bb = b - 256; mt = bb >> 6; nt = bb & 63; A = R1old; B = B2T; }
    const int M0 = mt << 6, N0 = nt << 6;

    const int lane = tid & 63;
    const int wave = tid >> 6;
    const int wm = (wave >> 1) << 5;
    const int wn = (wave & 1) << 5;
    const int fr = lane & 15;
    const int fq = lane >> 4;
    const bool s3blk = g1 && (nt == 0);          // block-uniform
    const bool doS3 = s3blk && (wn == 0);        // wave-uniform

    f32x4 acc[4], acc2[2];
    f32x4 zero = {0.f, 0.f, 0.f, 0.f};
#pragma unroll
    for (int i = 0; i < 4; ++i) acc[i] = zero;
    acc2[0] = zero; acc2[1] = zero;

    gemm_core(A, B, 4096, M0, N0, ldsA, ldsB, ldsS, acc,
              FW2T, acc2, s3blk, doS3, tid);

    if (g1) {
#pragma unroll
        for (int i = 0; i < 4; ++i) {
            int im = i >> 1, in_ = i & 1;
            int n = N0 + wn + (in_ << 4) + fr;
#pragma unroll
            for (int rr = 0; rr < 4; ++rr) {
                int m = M0 + wm + (im << 4) + (fq << 2) + rr;
                size_t o = (size_t)m * 4096 + n;
                float v = 0.5f * S1old[o] + CC[o] + 0.25f * acc[i][rr];
                v = clamp01(v);
                S1new[o] = v;
                R1new[o] = f2b(v);
            }
        }
        if (doS3 && fr < 10) {
#pragma unroll
            for (int im = 0; im < 2; ++im) {
#pragma unroll
                for (int rr = 0; rr < 4; ++rr) {
                    int m = M0 + wm + (im << 4) + (fq << 2) + rr;
                    float s3 = S3old[m * 10 + fr];
                    float v = (0.5f - beta) * s3 + 0.5f * acc2[im][rr]
                              + beta * y[m * 10 + fr];
                    v = clamp01(v);
                    S3new[m * 10 + fr] = v;
                }
            }
        }
    } else {
#pragma unroll
        for (int i = 0; i < 4; ++i) {
            int im = i >> 1, in_ = i & 1;
            int n = N0 + wn + (in_ << 4) + fr;
#pragma unroll
            for (int rr = 0; rr < 4; ++rr) {
                int m = M0 + wm + (im << 4) + (fq << 2) + rr;
                size_t o = (size_t)m * 4096 + n;
                float dot = 0.f;
#pragma unroll
                for (int j = 0; j < 10; ++j)
                    dot += S3old[m * 10 + j] * bw2[j * 4096 + n];
                float v = 0.5f * S2old[o] + 0.25f * acc[i][rr] + 0.25f * dot;
                v = clamp01(v);
                S2new[o] = v;
                R2new[o] = f2b(v);
            }
        }
    }
}

// CC = 0.25*(rx @ fw0). A = RX [256,1024] bf16, B = FW0T [4096,1024] bf16.
// 64x64 tiles -> 256 blocks.
__global__ __launch_bounds__(256) void c1_kernel(
    const unsigned short* __restrict__ RX,
    const unsigned short* __restrict__ FW0T,
    float* __restrict__ CC)
{
    __shared__ __align__(16) unsigned short ldsA[4][64 * 64];
    __shared__ __align__(16) unsigned short ldsB[4][64 * 64];
    __shared__ __align__(16) unsigned short ldsS[4][16 * 64];
    const int tid = threadIdx.x;
    const int b = blockIdx.x;
    const int mt = b >> 6, nt = b & 63;
    const int M0 = mt << 6, N0 = nt << 6;

    f32x4 acc[4], acc2[2];
    f32x4 zero = {0.f, 0.f, 0.f, 0.f};
#pragma unroll
    for (int i = 0; i < 4; ++i) acc[i] = zero;
    acc2[0] = zero; acc2[1] = zero;

    gemm_core(RX, FW0T, 1024, M0, N0, ldsA, ldsB, ldsS, acc,
              nullptr, acc2, false, false, tid);

    const int lane = tid & 63;
    const int wave = tid >> 6;
    const int wm = (wave >> 1) << 5;
    const int wn = (wave & 1) << 5;
    const int fr = lane & 15;
    const int fq = lane >> 4;
#pragma unroll
    for (int i = 0; i < 4; ++i) {
        int im = i >> 1, in_ = i & 1;
        int n = N0 + wn + (in_ << 4) + fr;
#pragma unroll
        for (int rr = 0; rr < 4; ++rr) {
            int m = M0 + wm + (im << 4) + (fq << 2) + rr;
            CC[(size_t)m * 4096 + n] = 0.25f * acc[i][rr];
        }
    }
}

// src [R][C] fp32 row-major -> dst [C][R] bf16 (dst row stride = R).
__global__ __launch_bounds__(256) void transpose_cvt(
    const float* __restrict__ src, unsigned short* __restrict__ dst,
    int R, int C)
{
    __shared__ float t[32][33];
    const int c0 = blockIdx.x << 5, r0 = blockIdx.y << 5;
    const int tx = threadIdx.x & 31, ty = threadIdx.x >> 5;   // ty: 0..7
#pragma unroll
    for (int i = 0; i < 32; i += 8)
        t[ty + i][tx] = src[(size_t)(r0 + ty + i) * C + (c0 + tx)];
    __syncthreads();
#pragma unroll
    for (int i = 0; i < 32; i += 8)
        dst[(size_t)(c0 + ty + i) * R + (r0 + tx)] = f2b(t[tx][ty + i]);
}

// FW2T fill, rx convert, zero-init of ping buffers.
__global__ __launch_bounds__(256) void misc_init(
    const float* __restrict__ x, const float* __restrict__ fw2,
    unsigned short* __restrict__ FW2T, unsigned short* __restrict__ RX,
    float* __restrict__ S1, float* __restrict__ S2, float* __restrict__ S3,
    unsigned short* __restrict__ R1, unsigned short* __restrict__ R2)
{
    const int stride = gridDim.x * blockDim.x;
    const int t0 = blockIdx.x * blockDim.x + threadIdx.x;
    for (int i = t0; i < 16 * 4096; i += stride) {      // FW2T[n][k] = fw2[k][n]
        int n = i >> 12, k = i & 4095;
        FW2T[i] = (n < 10) ? f2b(fw2[k * 10 + n]) : (unsigned short)0;
    }
    for (int i = t0; i < 256 * 1024; i += stride)
        RX[i] = f2b(clamp01(x[i]));
    for (int i = t0; i < 256 * 4096; i += stride) {
        S1[i] = 0.f; S2[i] = 0.f; R1[i] = 0; R2[i] = 0;
    }
    for (int i = t0; i < 2560; i += stride) S3[i] = 0.f;
}

__global__ __launch_bounds__(256) void pack_kernel(
    const float* __restrict__ S1, const float* __restrict__ S2,
    const float* __restrict__ S3, float* __restrict__ out)
{
    const int stride = gridDim.x * blockDim.x;
    for (int i = blockIdx.x * blockDim.x + threadIdx.x; i < 256 * 8202; i += stride) {
        int m = i / 8202, c = i - m * 8202;
        float v;
        if (c < 4096)       v = S1[(size_t)m * 4096 + c];
        else if (c < 8192)  v = S2[(size_t)m * 4096 + (c - 4096)];
        else                v = S3[m * 10 + (c - 8192)];
        out[i] = v;
    }
}

extern "C" void kernel_launch(void* const* d_in, const int* in_sizes, int n_in,
                              void* d_out, int out_size, void* d_ws, size_t ws_size,
                              hipStream_t stream) {
    const float* x   = (const float*)d_in[0];
    const float* fw0 = (const float*)d_in[1];
    const float* fw1 = (const float*)d_in[2];
    const float* fw2 = (const float*)d_in[3];
    // d_in[4] = bw0 : unused by the reference
    const float* bw1 = (const float*)d_in[5];
    const float* bw2 = (const float*)d_in[6];
    const float* y   = (const float*)d_in[7];

    char* ws = (char*)d_ws;
    // workspace layout (bytes)
    unsigned short* B1T  = (unsigned short*)(ws + 0);          // 4096x4096 bf16
    unsigned short* B2T  = (unsigned short*)(ws + 33554432);   // 4096x4096 bf16
    unsigned short* FW0T = (unsigned short*)(ws + 67108864);   // 4096x1024 bf16
    unsigned short* FW2T = (unsigned short*)(ws + 75497472);   // 16x4096 bf16
    unsigned short* RX   = (unsigned short*)(ws + 75628544);   // 256x1024 bf16
    float*          CC   = (float*)(ws + 76152832);            // 256x4096 f32
    float*          S1f  = (float*)(ws + 80347136);            // 2 x 256x4096 f32
    float*          S2f  = (float*)(ws + 88735744);            // 2 x 256x4096 f32
    float*          S3f  = (float*)(ws + 97124352);            // 2 x 256x10 f32
    unsigned short* R1   = (unsigned short*)(ws + 97144832);   // 2 x 256x4096 bf16
    unsigned short* R2   = (unsigned short*)(ws + 101339136);  // 2 x 256x4096 bf16
    // total ~105.6 MB

    const size_t SB = 256 * 4096;  // state buffer elems
    dim3 blk(256);

    transpose_cvt<<<dim3(128, 128), blk, 0, stream>>>(bw1, B1T, 4096, 4096);
    transpose_cvt<<<dim3(128, 128), blk, 0, stream>>>(fw1, B2T, 4096, 4096);
    transpose_cvt<<<dim3(128, 32),  blk, 0, stream>>>(fw0, FW0T, 1024, 4096);
    misc_init<<<512, blk, 0, stream>>>(x, fw2, FW2T, RX,
                                       S1f, S2f, S3f, R1, R2);
    c1_kernel<<<256, blk, 0, stream>>>(RX, FW0T, CC);

    for (int t = 0; t < 25; ++t) {
        const int o = t & 1, nw = o ^ 1;
        const float beta = (t < 20) ? 0.0f : 0.5f;
        step_kernel<<<512, blk, 0, stream>>>(
            R2 + o * SB, R1 + o * SB,
            S1f + o * SB, S2f + o * SB, S3f + o * 2560,
            S1f + nw * SB, S2f + nw * SB, S3f + nw * 2560,
            R1 + nw * SB, R2 + nw * SB,
            B1T, B2T, FW2T, CC, bw2, y, beta);
    }

    pack_kernel<<<2048, blk, 0, stream>>>(S1f + SB, S2f + SB, S3f + 2560,
                                          (float*)d_out);
}